// Round 11
// baseline (209.236 us; speedup 1.0000x reference)
//
#include <hip/hip_runtime.h>

#define N_NODES 100000
#define N_EDGES 1600000

typedef __attribute__((ext_vector_type(8))) short short8;
typedef __attribute__((ext_vector_type(4))) float f32x4;
typedef __attribute__((ext_vector_type(2))) unsigned short ushort2v;
typedef __attribute__((ext_vector_type(4))) unsigned short ushort4v;
typedef __attribute__((ext_vector_type(8))) unsigned short ushort8v;

static __device__ inline unsigned short f2bf(float f) {
    union { float f; unsigned u; } v; v.f = f;
    unsigned r = v.u + 0x7FFF + ((v.u >> 16) & 1);   // round-to-nearest-even
    return (unsigned short)(r >> 16);
}
static __device__ inline float bf2f(unsigned short u) {
    union { unsigned u; float f; } v; v.u = ((unsigned)u) << 16;
    return v.f;
}

// ---------------- row_ptr via binary search over sorted dst ----------------
__global__ __launch_bounds__(256) void rowptr_k(const int* __restrict__ dst,
                                                int* __restrict__ rp) {
    int t = blockIdx.x * blockDim.x + threadIdx.x;
    if (t > N_NODES) return;
    int lo = 0, hi = N_EDGES;
    while (lo < hi) {
        int mid = (lo + hi) >> 1;
        if (dst[mid] < t) lo = mid + 1; else hi = mid;
    }
    rp[t] = lo;
}

// ---------------- weight prep: transpose + bf16 ----------------------------
__global__ __launch_bounds__(256) void prep_k(const float* __restrict__ w1,
                                              const float* __restrict__ w2,
                                              const float* __restrict__ l0w,
                                              unsigned short* __restrict__ w1t,
                                              unsigned short* __restrict__ w2t,
                                              unsigned short* __restrict__ w0t) {
    int id = blockIdx.x * blockDim.x + threadIdx.x;
    if (id < 128 * 160) {
        int o = id / 160, k = id - o * 160;
        w1t[id] = (k < 144) ? f2bf(w1[k * 128 + o]) : (unsigned short)0;
    } else if (id < 128 * 160 + 64 * 128) {
        int j = id - 128 * 160;
        int o = j / 128, k = j - o * 128;
        w2t[j] = f2bf(w2[k * 64 + o]);
    } else if (id < 128 * 160 + 64 * 128 + 80 * 64) {
        int j = id - 128 * 160 - 64 * 128;
        int o = j / 64, k = j - o * 64;
        w0t[j] = (o < 72 && k < 36) ? f2bf(l0w[k * 72 + o]) : (unsigned short)0;
    }
}

// ---------------- x -> bf16 [N][4] (pad col3 = 0) --------------------------
__global__ __launch_bounds__(256) void x2b_k(const float* __restrict__ x,
                                             unsigned short* __restrict__ xb4) {
    int t = blockIdx.x * blockDim.x + threadIdx.x;
    if (t >= N_NODES) return;
    ushort4v w;
    w[0] = f2bf(x[(size_t)t * 3 + 0]);
    w[1] = f2bf(x[(size_t)t * 3 + 1]);
    w[2] = f2bf(x[(size_t)t * 3 + 2]);
    w[3] = 0;
    *reinterpret_cast<ushort4v*>(xb4 + (size_t)t * 4) = w;
}

// ==== 4-way edge-split helpers: id = t*4+p; lanes of a node are adjacent ===
// Each lane gathers ALL channels for its quarter of the edge list (1-2 wide
// requests/edge), partials combined via shfl_xor(1)+shfl_xor(2).

// ---------------- conv1: gather xb4 (1 x 8B req/edge) ----------------------
__global__ __launch_bounds__(256) void conv1p_k(const unsigned short* __restrict__ xb4,
                                                const float* __restrict__ kv,
                                                const int* __restrict__ src,
                                                const int* __restrict__ rp,
                                                unsigned short* __restrict__ hcb) {
    int id = blockIdx.x * blockDim.x + threadIdx.x;
    if (id >= N_NODES * 4) return;
    int t = id >> 2;
    int p = id & 3;
    int e0 = rp[t], e1 = rp[t + 1];
    int q = (e1 - e0 + 3) >> 2;
    int s0 = e0 + p * q; if (s0 > e1) s0 = e1;
    int s1 = s0 + q;     if (s1 > e1) s1 = e1;

    float a0[3] = {0.f, 0.f, 0.f}, a1[3] = {0.f, 0.f, 0.f};
    int e = s0;
    for (; e + 4 <= s1; e += 4) {
        int s[4]; float k0[4], k1[4];
#pragma unroll
        for (int u = 0; u < 4; ++u) s[u]  = src[e + u];
#pragma unroll
        for (int u = 0; u < 4; ++u) k0[u] = kv[e + u];
#pragma unroll
        for (int u = 0; u < 4; ++u) k1[u] = kv[N_EDGES + e + u];
        ushort4v v[4];
#pragma unroll
        for (int u = 0; u < 4; ++u)
            v[u] = *reinterpret_cast<const ushort4v*>(xb4 + (size_t)s[u] * 4);
#pragma unroll
        for (int u = 0; u < 4; ++u) {
#pragma unroll
            for (int c = 0; c < 3; ++c) {
                float x = bf2f(v[u][c]);
                a0[c] += k0[u] * x;
                a1[c] += k1[u] * x;
            }
        }
    }
    for (; e < s1; ++e) {
        int s = src[e];
        float k0 = kv[e], k1 = kv[N_EDGES + e];
        ushort4v v = *reinterpret_cast<const ushort4v*>(xb4 + (size_t)s * 4);
#pragma unroll
        for (int c = 0; c < 3; ++c) {
            float x = bf2f(v[c]);
            a0[c] += k0 * x;
            a1[c] += k1 * x;
        }
    }
#pragma unroll
    for (int c = 0; c < 3; ++c) {
        a0[c] += __shfl_xor(a0[c], 1); a0[c] += __shfl_xor(a0[c], 2);
        a1[c] += __shfl_xor(a1[c], 1); a1[c] += __shfl_xor(a1[c], 2);
    }
    if (p == 0) {
        ushort4v w4; ushort2v w2;
        w4[0] = f2bf(a0[0]); w4[1] = f2bf(a0[1]); w4[2] = f2bf(a0[2]); w4[3] = f2bf(a1[0]);
        w2[0] = f2bf(a1[1]); w2[1] = f2bf(a1[2]);
        *reinterpret_cast<ushort4v*>(hcb + (size_t)t * 32)     = w4;
        *reinterpret_cast<ushort2v*>(hcb + (size_t)t * 32 + 4) = w2;
    }
}

// ---------------- fused conv2 + conv3a: one h1 gather (16B), 4 weights -----
// h2 (kdd) -> hcb cols 8..19; h3 part-a (kda) -> h3b cols 0..5 & 18..23
__global__ __launch_bounds__(256) void f23ap_k(const unsigned short* __restrict__ hcbr,
                                               const float* __restrict__ kdd,
                                               const float* __restrict__ kda,
                                               const int* __restrict__ src,
                                               const int* __restrict__ rp,
                                               unsigned short* __restrict__ hcbw,
                                               unsigned short* __restrict__ h3b) {
    int id = blockIdx.x * blockDim.x + threadIdx.x;
    if (id >= N_NODES * 4) return;
    int t = id >> 2;
    int p = id & 3;
    int e0 = rp[t], e1 = rp[t + 1];
    int q = (e1 - e0 + 3) >> 2;
    int s0 = e0 + p * q; if (s0 > e1) s0 = e1;
    int s1 = s0 + q;     if (s1 > e1) s1 = e1;

    float dd0[6], dd1[6], da0[6], da1[6];
#pragma unroll
    for (int c = 0; c < 6; ++c) { dd0[c] = dd1[c] = da0[c] = da1[c] = 0.f; }

    int e = s0;
    for (; e + 4 <= s1; e += 4) {
        int s[4]; float d0[4], d1[4], g0[4], g1[4];
#pragma unroll
        for (int u = 0; u < 4; ++u) s[u]  = src[e + u];
#pragma unroll
        for (int u = 0; u < 4; ++u) d0[u] = kdd[e + u];
#pragma unroll
        for (int u = 0; u < 4; ++u) d1[u] = kdd[N_EDGES + e + u];
#pragma unroll
        for (int u = 0; u < 4; ++u) g0[u] = kda[e + u];
#pragma unroll
        for (int u = 0; u < 4; ++u) g1[u] = kda[N_EDGES + e + u];
        ushort8v v[4];
#pragma unroll
        for (int u = 0; u < 4; ++u)
            v[u] = *reinterpret_cast<const ushort8v*>(hcbr + (size_t)s[u] * 32);
#pragma unroll
        for (int u = 0; u < 4; ++u) {
#pragma unroll
            for (int c = 0; c < 6; ++c) {
                float x = bf2f(v[u][c]);
                dd0[c] += d0[u] * x;
                dd1[c] += d1[u] * x;
                da0[c] += g0[u] * x;
                da1[c] += g1[u] * x;
            }
        }
    }
    for (; e < s1; ++e) {
        int s = src[e];
        float d0 = kdd[e], d1 = kdd[N_EDGES + e];
        float g0 = kda[e], g1 = kda[N_EDGES + e];
        ushort8v v = *reinterpret_cast<const ushort8v*>(hcbr + (size_t)s * 32);
#pragma unroll
        for (int c = 0; c < 6; ++c) {
            float x = bf2f(v[c]);
            dd0[c] += d0 * x;
            dd1[c] += d1 * x;
            da0[c] += g0 * x;
            da1[c] += g1 * x;
        }
    }
#pragma unroll
    for (int c = 0; c < 6; ++c) {
        dd0[c] += __shfl_xor(dd0[c], 1); dd0[c] += __shfl_xor(dd0[c], 2);
        dd1[c] += __shfl_xor(dd1[c], 1); dd1[c] += __shfl_xor(dd1[c], 2);
        da0[c] += __shfl_xor(da0[c], 1); da0[c] += __shfl_xor(da0[c], 2);
        da1[c] += __shfl_xor(da1[c], 1); da1[c] += __shfl_xor(da1[c], 2);
    }
    if (p == 0) {
        // h2 -> hcb cols 8..19
        ushort8v w8; ushort4v w4;
        w8[0] = f2bf(dd0[0]); w8[1] = f2bf(dd0[1]); w8[2] = f2bf(dd0[2]);
        w8[3] = f2bf(dd0[3]); w8[4] = f2bf(dd0[4]); w8[5] = f2bf(dd0[5]);
        w8[6] = f2bf(dd1[0]); w8[7] = f2bf(dd1[1]);
        w4[0] = f2bf(dd1[2]); w4[1] = f2bf(dd1[3]); w4[2] = f2bf(dd1[4]); w4[3] = f2bf(dd1[5]);
        *reinterpret_cast<ushort8v*>(hcbw + (size_t)t * 32 + 8)  = w8;
        *reinterpret_cast<ushort4v*>(hcbw + (size_t)t * 32 + 16) = w4;
        // h3 part-a -> h3b cols 0..5 and 18..23
        ushort4v h4; ushort2v h2;
        h4[0] = f2bf(da0[0]); h4[1] = f2bf(da0[1]); h4[2] = f2bf(da0[2]); h4[3] = f2bf(da0[3]);
        h2[0] = f2bf(da0[4]); h2[1] = f2bf(da0[5]);
        *reinterpret_cast<ushort4v*>(h3b + (size_t)t * 64)     = h4;
        *reinterpret_cast<ushort2v*>(h3b + (size_t)t * 64 + 4) = h2;
        ushort2v ha, hb, hc;
        ha[0] = f2bf(da1[0]); ha[1] = f2bf(da1[1]);
        hb[0] = f2bf(da1[2]); hb[1] = f2bf(da1[3]);
        hc[0] = f2bf(da1[4]); hc[1] = f2bf(da1[5]);
        *reinterpret_cast<ushort2v*>(h3b + (size_t)t * 64 + 18) = ha;
        *reinterpret_cast<ushort2v*>(h3b + (size_t)t * 64 + 20) = hb;
        *reinterpret_cast<ushort2v*>(h3b + (size_t)t * 64 + 22) = hc;
    }
}

// ---------------- conv3b: gather h2 (hcb cols 8..19, 16B+8B), kda ----------
// -> h3b cols 6..17 (kernel 0) and 24..35 (kernel 1); zero pad 36..63
__global__ __launch_bounds__(256) void conv3bp_k(const unsigned short* __restrict__ hcb,
                                                 const float* __restrict__ kda,
                                                 const int* __restrict__ src,
                                                 const int* __restrict__ rp,
                                                 unsigned short* __restrict__ h3b) {
    int id = blockIdx.x * blockDim.x + threadIdx.x;
    if (id >= N_NODES * 4) return;
    int t = id >> 2;
    int p = id & 3;
    int e0 = rp[t], e1 = rp[t + 1];
    int q = (e1 - e0 + 3) >> 2;
    int s0 = e0 + p * q; if (s0 > e1) s0 = e1;
    int s1 = s0 + q;     if (s1 > e1) s1 = e1;

    float a0[12], a1[12];
#pragma unroll
    for (int c = 0; c < 12; ++c) { a0[c] = 0.f; a1[c] = 0.f; }

    int e = s0;
    for (; e + 4 <= s1; e += 4) {
        int s[4]; float g0[4], g1[4];
#pragma unroll
        for (int u = 0; u < 4; ++u) s[u]  = src[e + u];
#pragma unroll
        for (int u = 0; u < 4; ++u) g0[u] = kda[e + u];
#pragma unroll
        for (int u = 0; u < 4; ++u) g1[u] = kda[N_EDGES + e + u];
        ushort8v va[4]; ushort4v vb[4];
#pragma unroll
        for (int u = 0; u < 4; ++u) {
            va[u] = *reinterpret_cast<const ushort8v*>(hcb + (size_t)s[u] * 32 + 8);
            vb[u] = *reinterpret_cast<const ushort4v*>(hcb + (size_t)s[u] * 32 + 16);
        }
#pragma unroll
        for (int u = 0; u < 4; ++u) {
#pragma unroll
            for (int c = 0; c < 8; ++c) {
                float x = bf2f(va[u][c]);
                a0[c] += g0[u] * x;
                a1[c] += g1[u] * x;
            }
#pragma unroll
            for (int c = 0; c < 4; ++c) {
                float x = bf2f(vb[u][c]);
                a0[8 + c] += g0[u] * x;
                a1[8 + c] += g1[u] * x;
            }
        }
    }
    for (; e < s1; ++e) {
        int s = src[e];
        float g0 = kda[e], g1 = kda[N_EDGES + e];
        ushort8v va = *reinterpret_cast<const ushort8v*>(hcb + (size_t)s * 32 + 8);
        ushort4v vb = *reinterpret_cast<const ushort4v*>(hcb + (size_t)s * 32 + 16);
#pragma unroll
        for (int c = 0; c < 8; ++c) {
            float x = bf2f(va[c]);
            a0[c] += g0 * x; a1[c] += g1 * x;
        }
#pragma unroll
        for (int c = 0; c < 4; ++c) {
            float x = bf2f(vb[c]);
            a0[8 + c] += g0 * x; a1[8 + c] += g1 * x;
        }
    }
#pragma unroll
    for (int c = 0; c < 12; ++c) {
        a0[c] += __shfl_xor(a0[c], 1); a0[c] += __shfl_xor(a0[c], 2);
        a1[c] += __shfl_xor(a1[c], 1); a1[c] += __shfl_xor(a1[c], 2);
    }
    if (p == 0) {
        unsigned short* o = h3b + (size_t)t * 64;
        // kernel 0 -> cols 6..17
        ushort2v w2; ushort8v w8; ushort2v w2b;
        w2[0] = f2bf(a0[0]); w2[1] = f2bf(a0[1]);
#pragma unroll
        for (int c = 0; c < 8; ++c) w8[c] = f2bf(a0[2 + c]);
        w2b[0] = f2bf(a0[10]); w2b[1] = f2bf(a0[11]);
        *reinterpret_cast<ushort2v*>(o + 6)  = w2;
        *reinterpret_cast<ushort8v*>(o + 8)  = w8;
        *reinterpret_cast<ushort2v*>(o + 16) = w2b;
        // kernel 1 -> cols 24..35
        ushort8v x8; ushort4v x4;
#pragma unroll
        for (int c = 0; c < 8; ++c) x8[c] = f2bf(a1[c]);
#pragma unroll
        for (int c = 0; c < 4; ++c) x4[c] = f2bf(a1[8 + c]);
        *reinterpret_cast<ushort8v*>(o + 24) = x8;
        *reinterpret_cast<ushort4v*>(o + 32) = x4;
        // zero pad cols 36..63
        ushort4v z = {0, 0, 0, 0};
#pragma unroll
        for (int j = 36; j < 64; j += 4)
            *reinterpret_cast<ushort4v*>(o + j) = z;
    }
}

template<int VEC> struct VecU;
template<> struct VecU<4> { using T = ushort4v; };
template<> struct VecU<8> { using T = ushort8v; };

// ---------------- bf16 aniso conv (conv4, byte-bound at LLC path) ----------
template<int C, int VEC, int IN_STRIDE, int OUT_STRIDE, int OUT_OFF,
         int PAD_FROM, int PAD_TO>
__global__ __launch_bounds__(256) void convb_k(const unsigned short* __restrict__ hin,
                                               const float* __restrict__ kv,
                                               const int* __restrict__ src,
                                               const int* __restrict__ rp,
                                               unsigned short* __restrict__ hout) {
    constexpr int G = C / VEC;
    using VT = typename VecU<VEC>::T;
    int id = blockIdx.x * blockDim.x + threadIdx.x;
    if (id >= N_NODES * G) return;
    int t = id / G;
    int g = id - t * G;
    int c0 = g * VEC;
    int e0 = rp[t], e1 = rp[t + 1];

    float a0[VEC], a1[VEC];
#pragma unroll
    for (int q = 0; q < VEC; ++q) { a0[q] = 0.f; a1[q] = 0.f; }

    int e = e0;
    for (; e + 8 <= e1; e += 8) {
        int s[8]; float k0[8], k1[8];
#pragma unroll
        for (int u = 0; u < 8; ++u) s[u]  = src[e + u];
#pragma unroll
        for (int u = 0; u < 8; ++u) k0[u] = kv[e + u];
#pragma unroll
        for (int u = 0; u < 8; ++u) k1[u] = kv[N_EDGES + e + u];
        VT v[8];
#pragma unroll
        for (int u = 0; u < 8; ++u)
            v[u] = *reinterpret_cast<const VT*>(hin + (size_t)s[u] * IN_STRIDE + c0);
#pragma unroll
        for (int u = 0; u < 8; ++u) {
#pragma unroll
            for (int q = 0; q < VEC; ++q) {
                float x = bf2f(v[u][q]);
                a0[q] += k0[u] * x;
                a1[q] += k1[u] * x;
            }
        }
    }
    for (; e < e1; ++e) {
        int s = src[e];
        float k0 = kv[e], k1 = kv[N_EDGES + e];
        VT v = *reinterpret_cast<const VT*>(hin + (size_t)s * IN_STRIDE + c0);
#pragma unroll
        for (int q = 0; q < VEC; ++q) {
            float x = bf2f(v[q]);
            a0[q] += k0 * x;
            a1[q] += k1 * x;
        }
    }

    VT r0, r1;
#pragma unroll
    for (int q = 0; q < VEC; ++q) { r0[q] = f2bf(a0[q]); r1[q] = f2bf(a1[q]); }
    *reinterpret_cast<VT*>(hout + (size_t)t * OUT_STRIDE + OUT_OFF + c0)     = r0;
    *reinterpret_cast<VT*>(hout + (size_t)t * OUT_STRIDE + OUT_OFF + C + c0) = r1;

    if constexpr (PAD_TO > PAD_FROM) {
        if (g == G - 1) {
            ushort4v z = {0, 0, 0, 0};
#pragma unroll
            for (int j = PAD_FROM; j < PAD_TO; j += 4)
                *reinterpret_cast<ushort4v*>(hout + (size_t)t * OUT_STRIDE + j) = z;
        }
    }
}

// ---------------- lin0 via MFMA: h4b = relu(h3b[N][64] @ w0t + b0) ---------
__global__ __launch_bounds__(256) void lin0m_k(const unsigned short* __restrict__ h3b,
                                               const unsigned short* __restrict__ w0t,
                                               const float* __restrict__ b0,
                                               unsigned short* __restrict__ h4b) {
    int tid = threadIdx.x;
    int w = tid >> 6;
    int lane = tid & 63;
    int lr = lane & 15;
    int kg = lane >> 4;
    int row_base = blockIdx.x * 64 + w * 16;

    f32x4 acc[5];
#pragma unroll
    for (int n = 0; n < 5; ++n) acc[n] = (f32x4){0.f, 0.f, 0.f, 0.f};

    const unsigned short* arow = h3b + (size_t)(row_base + lr) * 64 + kg * 8;
#pragma unroll
    for (int ks = 0; ks < 2; ++ks) {
        short8 a = *reinterpret_cast<const short8*>(arow + ks * 32);
#pragma unroll
        for (int n = 0; n < 5; ++n) {
            short8 b = *reinterpret_cast<const short8*>(w0t + (n * 16 + lr) * 64 + ks * 32 + kg * 8);
            acc[n] = __builtin_amdgcn_mfma_f32_16x16x32_bf16(a, b, acc[n], 0, 0, 0);
        }
    }
#pragma unroll
    for (int n = 0; n < 5; ++n) {
        int col = n * 16 + lr;
        if (col < 72) {
            float bv = b0[col];
#pragma unroll
            for (int q = 0; q < 4; ++q) {
                int t = row_base + kg * 4 + q;
                if (t < N_NODES)
                    h4b[(size_t)t * 72 + col] = f2bf(fmaxf(acc[n][q] + bv, 0.f));
            }
        }
    }
}

// ---------------- MFMA MLP head + L2 normalize -----------------------------
#define HSTRIDE 136
__global__ __launch_bounds__(256) void mlp_k(const unsigned short* __restrict__ h5b,
                                             const unsigned short* __restrict__ w1t,
                                             const float* __restrict__ b1,
                                             const unsigned short* __restrict__ w2t,
                                             const float* __restrict__ b2,
                                             float* __restrict__ out) {
    __shared__ unsigned short sh[64 * HSTRIDE];
    int tid = threadIdx.x;
    int w = tid >> 6;
    int lane = tid & 63;
    int lr = lane & 15;
    int kg = lane >> 4;
    int row_base = blockIdx.x * 64 + w * 16;

    f32x4 acc[8];
#pragma unroll
    for (int n = 0; n < 8; ++n) acc[n] = (f32x4){0.f, 0.f, 0.f, 0.f};

    const unsigned short* arow = h5b + (size_t)(row_base + lr) * 160 + kg * 8;
#pragma unroll
    for (int ks = 0; ks < 5; ++ks) {
        short8 a = *reinterpret_cast<const short8*>(arow + ks * 32);
#pragma unroll
        for (int n = 0; n < 8; ++n) {
            short8 b = *reinterpret_cast<const short8*>(w1t + (n * 16 + lr) * 160 + ks * 32 + kg * 8);
            acc[n] = __builtin_amdgcn_mfma_f32_16x16x32_bf16(a, b, acc[n], 0, 0, 0);
        }
    }
#pragma unroll
    for (int n = 0; n < 8; ++n) {
        float bv = b1[n * 16 + lr];
#pragma unroll
        for (int q = 0; q < 4; ++q) {
            float hv = fmaxf(acc[n][q] + bv, 0.f);
            sh[(w * 16 + kg * 4 + q) * HSTRIDE + n * 16 + lr] = f2bf(hv);
        }
    }
    __syncthreads();

    f32x4 acc2[4];
#pragma unroll
    for (int n = 0; n < 4; ++n) acc2[n] = (f32x4){0.f, 0.f, 0.f, 0.f};
#pragma unroll
    for (int ks = 0; ks < 4; ++ks) {
        short8 a = *reinterpret_cast<const short8*>(sh + (w * 16 + lr) * HSTRIDE + ks * 32 + kg * 8);
#pragma unroll
        for (int n = 0; n < 4; ++n) {
            short8 b = *reinterpret_cast<const short8*>(w2t + (n * 16 + lr) * 128 + ks * 32 + kg * 8);
            acc2[n] = __builtin_amdgcn_mfma_f32_16x16x32_bf16(a, b, acc2[n], 0, 0, 0);
        }
    }

    float v[4][4];
    float ss[4];
#pragma unroll
    for (int q = 0; q < 4; ++q) ss[q] = 0.f;
#pragma unroll
    for (int n = 0; n < 4; ++n) {
        float bv = b2[n * 16 + lr];
#pragma unroll
        for (int q = 0; q < 4; ++q) {
            float x = acc2[n][q] + bv;
            v[n][q] = x;
            ss[q] += x * x;
        }
    }
#pragma unroll
    for (int q = 0; q < 4; ++q) {
#pragma unroll
        for (int d = 1; d < 16; d <<= 1) ss[q] += __shfl_xor(ss[q], d);
    }
#pragma unroll
    for (int q = 0; q < 4; ++q) {
        int node = row_base + kg * 4 + q;
        if (node < N_NODES) {
            float scale = 1.f / fmaxf(sqrtf(ss[q]), 1e-12f);
#pragma unroll
            for (int n = 0; n < 4; ++n)
                out[(size_t)node * 64 + n * 16 + lr] = v[n][q] * scale;
        }
    }
}

extern "C" void kernel_launch(void* const* d_in, const int* in_sizes, int n_in,
                              void* d_out, int out_size, void* d_ws, size_t ws_size,
                              hipStream_t stream) {
    const float* x   = (const float*)d_in[0];
    const float* kdd = (const float*)d_in[1];
    const float* kda = (const float*)d_in[2];
    const float* l0w = (const float*)d_in[3];
    const float* l0b = (const float*)d_in[4];
    const float* w1  = (const float*)d_in[5];
    const float* b1  = (const float*)d_in[6];
    const float* w2  = (const float*)d_in[7];
    const float* b2  = (const float*)d_in[8];
    const int*   src = (const int*)d_in[9];
    const int*   dst = (const int*)d_in[10];
    float* out = (float*)d_out;
    char* ws = (char*)d_ws;

    // workspace layout (bytes):
    //   rp    [0, +400004)
    //   w0t   [400384, +10240)       bf16 80x64
    //   w1t   [410624, +40960)       bf16 128x160
    //   w2t   [451584, +16384)       bf16 64x128
    //   hcb   [475136, +6.4 MB)      bf16 N*32 (64B rows: h1 @0..5, h2 @8..19)
    //   h3b   [6875136, +12.80 MB)   bf16 100032*64 (K-padded)
    //   h4b   [19679232, +14.4 MB)   bf16 N*72
    //   h5b   [34079232, +32.01 MB)  bf16 100032*160
    //   xb4   [34079232, +800 KB)    bf16 N*4 — overlays h5b head (dead
    //                                before conv4 writes h5b)
    int*   rp  = (int*)ws;
    unsigned short* w0t = (unsigned short*)(ws + 400384u);
    unsigned short* w1t = (unsigned short*)(ws + 410624u);
    unsigned short* w2t = (unsigned short*)(ws + 451584u);
    unsigned short* hcb = (unsigned short*)(ws + 475136u);
    unsigned short* h3b = (unsigned short*)(ws + 6875136u);
    unsigned short* h4b = (unsigned short*)(ws + 19679232u);
    unsigned short* h5b = (unsigned short*)(ws + 34079232u);
    unsigned short* xb4 = (unsigned short*)(ws + 34079232u);

    int nb4 = (N_NODES * 4 + 255) / 256;
    rowptr_k<<<(N_NODES + 1 + 255) / 256, 256, 0, stream>>>(dst, rp);
    prep_k<<<(128 * 160 + 64 * 128 + 80 * 64 + 255) / 256, 256, 0, stream>>>(w1, w2, l0w, w1t, w2t, w0t);
    x2b_k<<<(N_NODES + 255) / 256, 256, 0, stream>>>(x, xb4);

    // DD phase + DA-h1 part (4-way edge-split, shfl-combined)
    conv1p_k<<<nb4, 256, 0, stream>>>(xb4, kdd, src, rp, hcb);
    f23ap_k<<<nb4, 256, 0, stream>>>(hcb, kdd, kda, src, rp, hcb, h3b);
    conv3bp_k<<<nb4, 256, 0, stream>>>(hcb, kda, src, rp, h3b);

    // DA tail
    lin0m_k<<<(N_NODES + 63) / 64, 256, 0, stream>>>(h3b, w0t, l0b, h4b);
    convb_k<72, 8, 72, 160, 0, 144, 160><<<(N_NODES * 9 + 255) / 256, 256, 0, stream>>>(h4b, kda, src, rp, h5b);

    // MFMA MLP head + normalize
    mlp_k<<<(N_NODES + 63) / 64, 256, 0, stream>>>(h5b, w1t, b1, w2t, b2, out);
}

// Round 12
// 197.940 us; speedup vs baseline: 1.0571x; 1.0571x over previous
//
#include <hip/hip_runtime.h>

#define N_NODES 100000
#define N_EDGES 1600000

typedef __attribute__((ext_vector_type(8))) short short8;
typedef __attribute__((ext_vector_type(4))) float f32x4;
typedef __attribute__((ext_vector_type(2))) unsigned short ushort2v;
typedef __attribute__((ext_vector_type(4))) unsigned short ushort4v;
typedef __attribute__((ext_vector_type(8))) unsigned short ushort8v;

static __device__ inline unsigned short f2bf(float f) {
    union { float f; unsigned u; } v; v.f = f;
    unsigned r = v.u + 0x7FFF + ((v.u >> 16) & 1);   // round-to-nearest-even
    return (unsigned short)(r >> 16);
}
static __device__ inline float bf2f(unsigned short u) {
    union { unsigned u; float f; } v; v.u = ((unsigned)u) << 16;
    return v.f;
}

// ---------------- setup: row_ptr (binary search) + weight prep, one kernel -
__global__ __launch_bounds__(256) void setup_k(const int* __restrict__ dst,
                                               int* __restrict__ rp,
                                               const float* __restrict__ w1,
                                               const float* __restrict__ w2,
                                               const float* __restrict__ l0w,
                                               unsigned short* __restrict__ w1t,
                                               unsigned short* __restrict__ w2t,
                                               unsigned short* __restrict__ w0t) {
    int id = blockIdx.x * blockDim.x + threadIdx.x;
    if (id <= N_NODES) {
        int lo = 0, hi = N_EDGES;
        while (lo < hi) {
            int mid = (lo + hi) >> 1;
            if (dst[mid] < id) lo = mid + 1; else hi = mid;
        }
        rp[id] = lo;
    }
    if (id < 128 * 160) {
        int o = id / 160, k = id - o * 160;
        w1t[id] = (k < 144) ? f2bf(w1[k * 128 + o]) : (unsigned short)0;
    } else if (id < 128 * 160 + 64 * 128) {
        int j = id - 128 * 160;
        int o = j / 128, k = j - o * 128;
        w2t[j] = f2bf(w2[k * 64 + o]);
    } else if (id < 128 * 160 + 64 * 128 + 80 * 64) {
        int j = id - 128 * 160 - 64 * 128;
        int o = j / 64, k = j - o * 64;
        w0t[j] = (o < 72 && k < 36) ? f2bf(l0w[k * 72 + o]) : (unsigned short)0;
    }
}

// ---------------- conv1: f32 in [N][3] -> bf16 hcb (stride 20) -------------
__global__ __launch_bounds__(256) void conv1_k(const float* __restrict__ hin,
                                               const float* __restrict__ kv,
                                               const int* __restrict__ src,
                                               const int* __restrict__ rp,
                                               unsigned short* __restrict__ hout) {
    int id = blockIdx.x * blockDim.x + threadIdx.x;
    if (id >= N_NODES * 3) return;
    int t = id / 3;
    int c = id - t * 3;
    int e0 = rp[t], e1 = rp[t + 1];
    float a0 = 0.f, a1 = 0.f;
    int e = e0;
    for (; e + 8 <= e1; e += 8) {
        int s[8]; float k0[8], k1[8], v[8];
#pragma unroll
        for (int u = 0; u < 8; ++u) s[u]  = src[e + u];
#pragma unroll
        for (int u = 0; u < 8; ++u) k0[u] = kv[e + u];
#pragma unroll
        for (int u = 0; u < 8; ++u) k1[u] = kv[N_EDGES + e + u];
#pragma unroll
        for (int u = 0; u < 8; ++u) v[u]  = hin[(size_t)s[u] * 3 + c];
#pragma unroll
        for (int u = 0; u < 8; ++u) { a0 += k0[u] * v[u]; a1 += k1[u] * v[u]; }
    }
    for (; e < e1; ++e) {
        int s = src[e];
        float v = hin[(size_t)s * 3 + c];
        a0 += kv[e] * v;
        a1 += kv[N_EDGES + e] * v;
    }
    hout[(size_t)t * 20 + c]     = f2bf(a0);
    hout[(size_t)t * 20 + 3 + c] = f2bf(a1);
}

template<int VEC> struct VecU;
template<> struct VecU<2> { using T = ushort2v; };
template<> struct VecU<4> { using T = ushort4v; };
template<> struct VecU<8> { using T = ushort8v; };

// ---------------- bf16 aniso conv (conv2/conv3/conv4) ----------------------
template<int C, int VEC, int IN_STRIDE, int OUT_STRIDE, int OUT_OFF,
         int PAD_FROM, int PAD_TO>
__global__ __launch_bounds__(256) void convb_k(const unsigned short* __restrict__ hin,
                                               const float* __restrict__ kv,
                                               const int* __restrict__ src,
                                               const int* __restrict__ rp,
                                               unsigned short* __restrict__ hout) {
    constexpr int G = C / VEC;
    using VT = typename VecU<VEC>::T;
    int id = blockIdx.x * blockDim.x + threadIdx.x;
    if (id >= N_NODES * G) return;
    int t = id / G;
    int g = id - t * G;
    int c0 = g * VEC;
    int e0 = rp[t], e1 = rp[t + 1];

    float a0[VEC], a1[VEC];
#pragma unroll
    for (int q = 0; q < VEC; ++q) { a0[q] = 0.f; a1[q] = 0.f; }

    int e = e0;
    for (; e + 8 <= e1; e += 8) {
        int s[8]; float k0[8], k1[8];
#pragma unroll
        for (int u = 0; u < 8; ++u) s[u]  = src[e + u];
#pragma unroll
        for (int u = 0; u < 8; ++u) k0[u] = kv[e + u];
#pragma unroll
        for (int u = 0; u < 8; ++u) k1[u] = kv[N_EDGES + e + u];
        VT v[8];
#pragma unroll
        for (int u = 0; u < 8; ++u)
            v[u] = *reinterpret_cast<const VT*>(hin + (size_t)s[u] * IN_STRIDE + c0);
#pragma unroll
        for (int u = 0; u < 8; ++u) {
#pragma unroll
            for (int q = 0; q < VEC; ++q) {
                float x = bf2f(v[u][q]);
                a0[q] += k0[u] * x;
                a1[q] += k1[u] * x;
            }
        }
    }
    for (; e < e1; ++e) {
        int s = src[e];
        float k0 = kv[e], k1 = kv[N_EDGES + e];
        VT v = *reinterpret_cast<const VT*>(hin + (size_t)s * IN_STRIDE + c0);
#pragma unroll
        for (int q = 0; q < VEC; ++q) {
            float x = bf2f(v[q]);
            a0[q] += k0 * x;
            a1[q] += k1 * x;
        }
    }

    VT r0, r1;
#pragma unroll
    for (int q = 0; q < VEC; ++q) { r0[q] = f2bf(a0[q]); r1[q] = f2bf(a1[q]); }
    *reinterpret_cast<VT*>(hout + (size_t)t * OUT_STRIDE + OUT_OFF + c0)     = r0;
    *reinterpret_cast<VT*>(hout + (size_t)t * OUT_STRIDE + OUT_OFF + C + c0) = r1;

    if constexpr (PAD_TO > PAD_FROM) {
        if (g == G - 1) {
            ushort4v z = {0, 0, 0, 0};
#pragma unroll
            for (int j = PAD_FROM; j < PAD_TO; j += 4)
                *reinterpret_cast<ushort4v*>(hout + (size_t)t * OUT_STRIDE + j) = z;
        }
    }
}

// ---------------- lin0 via MFMA: h4b = relu(h3b[N][64] @ w0t + b0) ---------
__global__ __launch_bounds__(256) void lin0m_k(const unsigned short* __restrict__ h3b,
                                               const unsigned short* __restrict__ w0t,
                                               const float* __restrict__ b0,
                                               unsigned short* __restrict__ h4b) {
    int tid = threadIdx.x;
    int w = tid >> 6;
    int lane = tid & 63;
    int lr = lane & 15;
    int kg = lane >> 4;
    int row_base = blockIdx.x * 64 + w * 16;

    f32x4 acc[5];
#pragma unroll
    for (int n = 0; n < 5; ++n) acc[n] = (f32x4){0.f, 0.f, 0.f, 0.f};

    const unsigned short* arow = h3b + (size_t)(row_base + lr) * 64 + kg * 8;
#pragma unroll
    for (int ks = 0; ks < 2; ++ks) {
        short8 a = *reinterpret_cast<const short8*>(arow + ks * 32);
#pragma unroll
        for (int n = 0; n < 5; ++n) {
            short8 b = *reinterpret_cast<const short8*>(w0t + (n * 16 + lr) * 64 + ks * 32 + kg * 8);
            acc[n] = __builtin_amdgcn_mfma_f32_16x16x32_bf16(a, b, acc[n], 0, 0, 0);
        }
    }
#pragma unroll
    for (int n = 0; n < 5; ++n) {
        int col = n * 16 + lr;
        if (col < 72) {
            float bv = b0[col];
#pragma unroll
            for (int q = 0; q < 4; ++q) {
                int t = row_base + kg * 4 + q;
                if (t < N_NODES)
                    h4b[(size_t)t * 72 + col] = f2bf(fmaxf(acc[n][q] + bv, 0.f));
            }
        }
    }
}

// ---------------- MFMA MLP head + L2 normalize -----------------------------
#define HSTRIDE 136
__global__ __launch_bounds__(256) void mlp_k(const unsigned short* __restrict__ h5b,
                                             const unsigned short* __restrict__ w1t,
                                             const float* __restrict__ b1,
                                             const unsigned short* __restrict__ w2t,
                                             const float* __restrict__ b2,
                                             float* __restrict__ out) {
    __shared__ unsigned short sh[64 * HSTRIDE];
    int tid = threadIdx.x;
    int w = tid >> 6;
    int lane = tid & 63;
    int lr = lane & 15;
    int kg = lane >> 4;
    int row_base = blockIdx.x * 64 + w * 16;

    f32x4 acc[8];
#pragma unroll
    for (int n = 0; n < 8; ++n) acc[n] = (f32x4){0.f, 0.f, 0.f, 0.f};

    const unsigned short* arow = h5b + (size_t)(row_base + lr) * 160 + kg * 8;
#pragma unroll
    for (int ks = 0; ks < 5; ++ks) {
        short8 a = *reinterpret_cast<const short8*>(arow + ks * 32);
#pragma unroll
        for (int n = 0; n < 8; ++n) {
            short8 b = *reinterpret_cast<const short8*>(w1t + (n * 16 + lr) * 160 + ks * 32 + kg * 8);
            acc[n] = __builtin_amdgcn_mfma_f32_16x16x32_bf16(a, b, acc[n], 0, 0, 0);
        }
    }
#pragma unroll
    for (int n = 0; n < 8; ++n) {
        float bv = b1[n * 16 + lr];
#pragma unroll
        for (int q = 0; q < 4; ++q) {
            float hv = fmaxf(acc[n][q] + bv, 0.f);
            sh[(w * 16 + kg * 4 + q) * HSTRIDE + n * 16 + lr] = f2bf(hv);
        }
    }
    __syncthreads();

    f32x4 acc2[4];
#pragma unroll
    for (int n = 0; n < 4; ++n) acc2[n] = (f32x4){0.f, 0.f, 0.f, 0.f};
#pragma unroll
    for (int ks = 0; ks < 4; ++ks) {
        short8 a = *reinterpret_cast<const short8*>(sh + (w * 16 + lr) * HSTRIDE + ks * 32 + kg * 8);
#pragma unroll
        for (int n = 0; n < 4; ++n) {
            short8 b = *reinterpret_cast<const short8*>(w2t + (n * 16 + lr) * 128 + ks * 32 + kg * 8);
            acc2[n] = __builtin_amdgcn_mfma_f32_16x16x32_bf16(a, b, acc2[n], 0, 0, 0);
        }
    }

    float v[4][4];
    float ss[4];
#pragma unroll
    for (int q = 0; q < 4; ++q) ss[q] = 0.f;
#pragma unroll
    for (int n = 0; n < 4; ++n) {
        float bv = b2[n * 16 + lr];
#pragma unroll
        for (int q = 0; q < 4; ++q) {
            float x = acc2[n][q] + bv;
            v[n][q] = x;
            ss[q] += x * x;
        }
    }
#pragma unroll
    for (int q = 0; q < 4; ++q) {
#pragma unroll
        for (int d = 1; d < 16; d <<= 1) ss[q] += __shfl_xor(ss[q], d);
    }
#pragma unroll
    for (int q = 0; q < 4; ++q) {
        int node = row_base + kg * 4 + q;
        if (node < N_NODES) {
            float scale = 1.f / fmaxf(sqrtf(ss[q]), 1e-12f);
#pragma unroll
            for (int n = 0; n < 4; ++n)
                out[(size_t)node * 64 + n * 16 + lr] = v[n][q] * scale;
        }
    }
}

extern "C" void kernel_launch(void* const* d_in, const int* in_sizes, int n_in,
                              void* d_out, int out_size, void* d_ws, size_t ws_size,
                              hipStream_t stream) {
    const float* x   = (const float*)d_in[0];
    const float* kdd = (const float*)d_in[1];
    const float* kda = (const float*)d_in[2];
    const float* l0w = (const float*)d_in[3];
    const float* l0b = (const float*)d_in[4];
    const float* w1  = (const float*)d_in[5];
    const float* b1  = (const float*)d_in[6];
    const float* w2  = (const float*)d_in[7];
    const float* b2  = (const float*)d_in[8];
    const int*   src = (const int*)d_in[9];
    const int*   dst = (const int*)d_in[10];
    float* out = (float*)d_out;
    char* ws = (char*)d_ws;

    // workspace layout (bytes):
    //   rp    [0, +400004)
    //   w0t   [400384, +10240)        bf16 80x64
    //   w1t   [410624, +40960)        bf16 128x160
    //   w2t   [451584, +16384)        bf16 64x128
    //   hcb   [475136, +4.0 MB)       bf16 N*20   (h1 cols 0:6, h2 cols 6:18)
    //   h3b   [4480000, +12.80 MB)    bf16 100032*64 (K-padded)
    //   h4b   [17284096, +14.4 MB)    bf16 N*72
    //   h5b   [31684096, +32.01 MB)   bf16 100032*160
    int*   rp  = (int*)ws;
    unsigned short* w0t = (unsigned short*)(ws + 400384u);
    unsigned short* w1t = (unsigned short*)(ws + 410624u);
    unsigned short* w2t = (unsigned short*)(ws + 451584u);
    unsigned short* hcb = (unsigned short*)(ws + 475136u);
    unsigned short* h3b = (unsigned short*)(ws + 4480000u);
    unsigned short* h4b = (unsigned short*)(ws + 17284096u);
    unsigned short* h5b = (unsigned short*)(ws + 31684096u);

    // setup: rowptr + weight prep in one dispatch
    setup_k<<<(N_NODES + 1 + 255) / 256, 256, 0, stream>>>(dst, rp, w1, w2, l0w, w1t, w2t, w0t);

    // DD phase: x[N,3] -> h1 (hcb cols 0:6) -> h2 (hcb cols 6:18)
    conv1_k<<<(N_NODES * 3 + 255) / 256, 256, 0, stream>>>(x, kdd, src, rp, hcb);
    convb_k<6, 2, 20, 20, 6, 0, 0><<<(N_NODES * 3 + 255) / 256, 256, 0, stream>>>(hcb, kdd, src, rp, hcb);

    // DA phase
    convb_k<18, 2, 20, 64, 0, 36, 64><<<(N_NODES * 9 + 255) / 256, 256, 0, stream>>>(hcb, kda, src, rp, h3b);
    lin0m_k<<<(N_NODES + 63) / 64, 256, 0, stream>>>(h3b, w0t, l0b, h4b);
    convb_k<72, 8, 72, 160, 0, 144, 160><<<(N_NODES * 9 + 255) / 256, 256, 0, stream>>>(h4b, kda, src, rp, h5b);

    // MFMA MLP head + normalize
    mlp_k<<<(N_NODES + 63) / 64, 256, 0, stream>>>(h5b, w1t, b1, w2t, b2, out);
}